// Round 9
// baseline (152.396 us; speedup 1.0000x reference)
//
#include <hip/hip_runtime.h>
#include <hip/hip_bf16.h>

typedef short v8s __attribute__((ext_vector_type(8)));
typedef float v4f __attribute__((ext_vector_type(4)));
typedef unsigned short u16;

#define KSPLIT 8

// ---- dual-dtype element access (f32m: 0 = bf16, 1 = f32) ----
static __device__ __forceinline__ float ldv(const void* p, size_t i, int f32m) {
    if (f32m) return ((const float*)p)[i];
    return __bfloat162float(((const __hip_bfloat16*)p)[i]);
}
static __device__ __forceinline__ void stv(void* p, size_t i, float v, int f32m) {
    if (f32m) ((float*)p)[i] = v;
    else ((__hip_bfloat16*)p)[i] = __float2bfloat16(v);
}
static __device__ __forceinline__ u16 f2bu(float x) {
    __hip_bfloat16 h = __float2bfloat16(x);
    return *(u16*)&h;
}
static __device__ __forceinline__ float bu2f(u16 u) {
    return __uint_as_float(((unsigned)u) << 16);
}
// 16B-aligned 4-wide load (requires i % 4 == 0 and aligned base)
static __device__ __forceinline__ v4f ldv4(const void* p, size_t i, int f32m) {
    if (f32m) return *(const v4f*)((const float*)p + i);
    ushort4 u = *(const ushort4*)((const u16*)p + i);
    v4f r; r[0] = bu2f(u.x); r[1] = bu2f(u.y); r[2] = bu2f(u.z); r[3] = bu2f(u.w);
    return r;
}

// Robust scalar decode: handles int32, float32, or bf16-in-low-16 encodings.
static __device__ __forceinline__ float decode_scalar(const void* p) {
    unsigned u = *(const unsigned*)p;
    unsigned e32 = (u >> 23) & 0xff;
    if (e32 >= 97 && e32 <= 160) return __uint_as_float(u);
    unsigned lo = u & 0xffffu;
    unsigned e16 = (lo >> 7) & 0xff;
    if ((u >> 16) == 0 && e16 >= 97 && e16 <= 160)
        return __uint_as_float(lo << 16);
    return (float)(int)u;
}

// Per-block dtype sniff (deterministic; contains a barrier — call unconditionally).
static __device__ __forceinline__ int block_sniff(const void* feat) {
    const __hip_bfloat16* p = (const __hip_bfloat16*)feat;
    float v = __bfloat162float(p[threadIdx.x & 255]);
    int bad = !(fabsf(v) < 1e10f);
    return __syncthreads_or(bad) ? 1 : 0;
}

__device__ __forceinline__ float wave_sum(float v) {
    #pragma unroll
    for (int o = 32; o > 0; o >>= 1) v += __shfl_down(v, o, 64);
    return v;
}
__device__ __forceinline__ float wave_max(float v) {
    #pragma unroll
    for (int o = 32; o > 0; o >>= 1) v = fmaxf(v, __shfl_down(v, o, 64));
    return v;
}

// async global->LDS, 16B per lane, LDS dst = wave-uniform base + lane*16
static __device__ __forceinline__ void ld16(u16* lds, const u16* g) {
    __builtin_amdgcn_global_load_lds(
        (const __attribute__((address_space(1))) unsigned int*)g,
        (__attribute__((address_space(3))) unsigned int*)lds,
        16, 0, 0);
}

// K1: prep (feat -> bf16 copy, 8 elems/thread) + block 0 extras:
//   - zero misc (loss accumulator + done counter)
//   - 256-thread counting sort of labels -> counts/offs/rows (CSR)
__global__ __launch_bounds__(256) void prep_sort(
        const void* __restrict__ feat, u16* __restrict__ featb, int total,
        const int* __restrict__ labels, int* __restrict__ counts,
        int* __restrict__ offs, int* __restrict__ rows,
        float* __restrict__ misc, int Nn, int C) {
    int f32m = block_sniff(feat);
    int tid = threadIdx.x;
    int i = (blockIdx.x * 256 + tid) * 8;
    if (i < total) {
        if (f32m) {
            const float* f = (const float*)feat + i;
            u16 r[8];
            #pragma unroll
            for (int u = 0; u < 8; ++u) r[u] = f2bu(f[u]);
            *(v8s*)(featb + i) = *(v8s*)r;
        } else {
            *(v8s*)(featb + i) = *(const v8s*)((const u16*)feat + i);
        }
    }
    if (blockIdx.x != 0) return;

    if (tid < 16) misc[tid] = 0.f;   // [0]=loss acc (f32), [1]=counter (int bits 0)

    __shared__ int h[1024];
    __shared__ int ex[256];
    __shared__ int cur[1024];
    #pragma unroll
    for (int u = 0; u < 4; ++u) h[tid + 256 * u] = 0;
    __syncthreads();
    for (int k = tid; k < Nn; k += 256) atomicAdd(&h[labels[k]], 1);
    __syncthreads();
    int b0 = h[4 * tid], b1 = h[4 * tid + 1], b2 = h[4 * tid + 2], b3 = h[4 * tid + 3];
    int s = b0 + b1 + b2 + b3;
    ex[tid] = s;
    __syncthreads();
    for (int d = 1; d < 256; d <<= 1) {
        int v = (tid >= d) ? ex[tid - d] : 0;
        __syncthreads();
        ex[tid] += v;
        __syncthreads();
    }
    int excl = ex[tid] - s;
    int o0 = excl, o1 = o0 + b0, o2 = o1 + b1, o3 = o2 + b2;
    counts[4 * tid] = b0; counts[4 * tid + 1] = b1;
    counts[4 * tid + 2] = b2; counts[4 * tid + 3] = b3;
    offs[4 * tid] = o0; offs[4 * tid + 1] = o1;
    offs[4 * tid + 2] = o2; offs[4 * tid + 3] = o3;
    cur[4 * tid] = o0; cur[4 * tid + 1] = o1;
    cur[4 * tid + 2] = o2; cur[4 * tid + 3] = o3;
    __syncthreads();
    for (int k = tid; k < Nn; k += 256) {
        int pos = atomicAdd(&cur[labels[k]], 1);
        rows[pos] = k;
    }
}

// K2: finalize stats, x4 vectorized. Block = (class c = blockIdx.y,
// 1024-col chunk = blockIdx.x); thread handles 4 consecutive cols.
__global__ __launch_bounds__(256) void finalize_stats(
        const u16* __restrict__ featb,
        const int* __restrict__ counts, const int* __restrict__ offs,
        const int* __restrict__ rows,
        const void* __restrict__ ave, const void* __restrict__ cov,
        const void* __restrict__ amount, const void* __restrict__ W,
        const void* __restrict__ feat,
        void* __restrict__ out, size_t off_ave, size_t off_cov, size_t off_amt,
        u16* __restrict__ Wb, u16* __restrict__ W2b,
        u16* __restrict__ Cb, u16* __restrict__ Gb,
        float* __restrict__ T3p, int A, int nch) {
    __shared__ float sb[4];
    int f32m = block_sniff(feat);
    int tid = threadIdx.x;
    int c = blockIdx.y;
    int a0 = blockIdx.x * 1024 + tid * 4;
    size_t idx = (size_t)c * A + a0;
    int cnti = counts[c];
    int start = offs[c];
    v4f s1 = {0,0,0,0}, s2 = {0,0,0,0};
    for (int i = 0; i < cnti; ++i) {
        ushort4 xu = *(const ushort4*)(featb + (size_t)rows[start + i] * A + a0);
        float x0 = bu2f(xu.x), x1 = bu2f(xu.y), x2 = bu2f(xu.z), x3 = bu2f(xu.w);
        s1[0] += x0; s1[1] += x1; s1[2] += x2; s1[3] += x3;
        s2[0] += x0 * x0; s2[1] += x1 * x1; s2[2] += x2 * x2; s2[3] += x3 * x3;
    }
    float cnt = (float)cnti;
    float denom = cnti > 0 ? cnt : 1.f;
    float amt = ldv(amount, c, f32m);
    float tot = cnt + amt;
    float w = tot > 0.f ? (cnt / tot) : 0.f;   // nan_to_num(0/0) -> 0
    v4f av = ldv4(ave, idx, f32m);
    v4f cv = ldv4(cov, idx, f32m);
    v4f wv = ldv4(W, idx, f32m);
    ushort4 oW, oW2, oC, oG;
    u16* pW = (u16*)&oW; u16* pW2 = (u16*)&oW2; u16* pC = (u16*)&oC; u16* pG = (u16*)&oG;
    float t3a = 0.f;
    #pragma unroll
    for (int e = 0; e < 4; ++e) {
        float mean = s1[e] / denom;
        float var = fmaxf((s2[e] - cnt * mean * mean) / denom, 0.f);
        float d = av[e] - mean;
        float ncv = cv[e] * (1.f - w) + var * w + w * (1.f - w) * d * d;
        float nav = av[e] * (1.f - w) + mean * w;
        stv(out, off_cov + idx + e, ncv, f32m);
        stv(out, off_ave + idx + e, nav, f32m);
        float wq = wv[e];
        pW[e] = f2bu(wq);
        pW2[e] = f2bu(wq * wq);
        pC[e] = f2bu(ncv);
        pG[e] = f2bu(ncv * wq);
        t3a += wq * wq * ncv;
    }
    *(ushort4*)(Wb + idx) = oW;
    *(ushort4*)(W2b + idx) = oW2;
    *(ushort4*)(Cb + idx) = oC;
    *(ushort4*)(Gb + idx) = oG;
    if (a0 == 0) stv(out, off_amt + c, amt + cnt, f32m);
    float s = wave_sum(t3a);
    int lane = tid & 63, wid = tid >> 6;
    if (lane == 0) sb[wid] = s;
    __syncthreads();
    if (tid == 0) T3p[(size_t)c * nch + blockIdx.x] = sb[0] + sb[1] + sb[2] + sb[3];
}

// K3: split-K fused MFMA triple GEMM, LDS-staged via global_load_lds.
// Tile 64n x 128j, BK=32, KSPLIT=8 -> grid (Cpad/128, Nn/64, 8) = 512 blocks.
// Per iter per wave: 7 DMAs (F,C,G rows + 2 W-subtiles + 2 W2-subtiles),
// 24 MFMAs (8 j-subtiles x 3 chains) between one barrier-pair.
__global__ __launch_bounds__(256) void triple_gemm_mfma(
        const u16* __restrict__ featb,
        const u16* __restrict__ Wb,
        const u16* __restrict__ W2b,
        const u16* __restrict__ Cb,
        const u16* __restrict__ Gb,
        const int* __restrict__ labels,
        float* __restrict__ partY, float* __restrict__ partT1, float* __restrict__ partT2,
        int Cpad, int A, size_t NC) {
    __shared__ u16 sA[14336];   // F:0 C:2048 G:4096 W:6144(8x512) W2:10240(8x512)
    __shared__ int sLab[64];
    int tid = threadIdx.x, wv = tid >> 6, lane = tid & 63;
    int n0 = blockIdx.y * 64, j0 = blockIdx.x * 128;
    int kslice = A / KSPLIT;
    int k0 = blockIdx.z * kslice;
    if (tid < 64) sLab[tid] = labels[n0 + tid];
    __syncthreads();

    int r = lane & 15, q = lane >> 4;
    int fr = wv * 16 + r;
    const u16* pF = featb + (size_t)(n0 + fr) * A + k0 + q * 8;
    int lab = sLab[fr];
    const u16* pC = Cb + (size_t)lab * A + k0 + q * 8;
    const u16* pG = Gb + (size_t)lab * A + k0 + q * 8;
    int s0 = wv * 2, s1 = wv * 2 + 1;            // B-subtiles this wave stages
    const u16* pW0 = Wb  + (size_t)(j0 + s0 * 16 + r) * A + k0 + q * 8;
    const u16* pW1 = Wb  + (size_t)(j0 + s1 * 16 + r) * A + k0 + q * 8;
    const u16* pQ0 = W2b + (size_t)(j0 + s0 * 16 + r) * A + k0 + q * 8;
    const u16* pQ1 = W2b + (size_t)(j0 + s1 * 16 + r) * A + k0 + q * 8;
    u16* dF  = &sA[0     + wv * 512];
    u16* dC  = &sA[2048  + wv * 512];
    u16* dG  = &sA[4096  + wv * 512];
    u16* dW0 = &sA[6144  + s0 * 512];
    u16* dW1 = &sA[6144  + s1 * 512];
    u16* dQ0 = &sA[10240 + s0 * 512];
    u16* dQ1 = &sA[10240 + s1 * 512];

    v4f aY[8]  = {{0,0,0,0},{0,0,0,0},{0,0,0,0},{0,0,0,0},{0,0,0,0},{0,0,0,0},{0,0,0,0},{0,0,0,0}};
    v4f aT1[8] = {{0,0,0,0},{0,0,0,0},{0,0,0,0},{0,0,0,0},{0,0,0,0},{0,0,0,0},{0,0,0,0},{0,0,0,0}};
    v4f aT2[8] = {{0,0,0,0},{0,0,0,0},{0,0,0,0},{0,0,0,0},{0,0,0,0},{0,0,0,0},{0,0,0,0},{0,0,0,0}};

    for (int kk = 0; kk < kslice; kk += 32) {
        ld16(dF, pF); ld16(dC, pC); ld16(dG, pG);
        ld16(dW0, pW0); ld16(dW1, pW1); ld16(dQ0, pQ0); ld16(dQ1, pQ1);
        pF += 32; pC += 32; pG += 32;
        pW0 += 32; pW1 += 32; pQ0 += 32; pQ1 += 32;
        __syncthreads();   // drains LDS-DMA (vmcnt) + joins waves
        v8s f = *(v8s*)&sA[0    + wv * 512 + lane * 8];
        v8s c = *(v8s*)&sA[2048 + wv * 512 + lane * 8];
        v8s g = *(v8s*)&sA[4096 + wv * 512 + lane * 8];
        #pragma unroll
        for (int t = 0; t < 8; ++t) {
            v8s w  = *(v8s*)&sA[6144  + t * 512 + lane * 8];
            v8s w2 = *(v8s*)&sA[10240 + t * 512 + lane * 8];
            aY[t]  = __builtin_amdgcn_mfma_f32_16x16x32_bf16(f, w,  aY[t],  0, 0, 0);
            aT1[t] = __builtin_amdgcn_mfma_f32_16x16x32_bf16(c, w2, aT1[t], 0, 0, 0);
            aT2[t] = __builtin_amdgcn_mfma_f32_16x16x32_bf16(g, w,  aT2[t], 0, 0, 0);
        }
        __syncthreads();
    }

    // C/D layout: col = lane&15, row = (lane>>4)*4 + reg.
    float* pY = partY + (size_t)blockIdx.z * NC;
    float* p1 = partT1 + (size_t)blockIdx.z * NC;
    float* p2 = partT2 + (size_t)blockIdx.z * NC;
    int quad = lane >> 4, colb = lane & 15;
    #pragma unroll
    for (int t = 0; t < 8; ++t) {
        int j = j0 + t * 16 + colb;
        #pragma unroll
        for (int rr = 0; rr < 4; ++rr) {
            int n = n0 + wv * 16 + quad * 4 + rr;
            size_t idx = (size_t)n * Cpad + j;
            pY[idx] = aY[t][rr];
            p1[idx] = aT1[t][rr];
            p2[idx] = aT2[t][rr];
        }
    }
}

// K4: fused epilogue + row loss + final mean, x4 vectorized (Cpad == 1024).
__global__ __launch_bounds__(256) void epilogue_rowloss(
        const float* __restrict__ partY, const float* __restrict__ partT1,
        const float* __restrict__ partT2, const float* __restrict__ T3p,
        const void* __restrict__ bias, const void* __restrict__ feat,
        const int* __restrict__ labels,
        void* __restrict__ out, size_t off_y,
        float* __restrict__ misc,
        int C, int Cpad, int nch, const void* ratio_p, size_t NC, int Nn) {
    __shared__ float sb[4];
    __shared__ float sM;
    __shared__ float sLabVal;
    int f32m = block_sniff(feat);
    int tid = threadIdx.x;
    int n = blockIdx.x;
    int lab = labels[n];
    float t3 = 0.f;
    for (int i = 0; i < nch; ++i) t3 += T3p[(size_t)lab * nch + i];
    float ratio = decode_scalar(ratio_p);

    int j0 = tid * 4;
    size_t idx = (size_t)n * Cpad + j0;
    v4f y = {0,0,0,0}, t1 = {0,0,0,0}, t2 = {0,0,0,0};
    #pragma unroll
    for (int z = 0; z < KSPLIT; ++z) {
        y  += *(const v4f*)(partY  + z * NC + idx);
        t1 += *(const v4f*)(partT1 + z * NC + idx);
        t2 += *(const v4f*)(partT2 + z * NC + idx);
    }
    v4f vals;
    float m = -3.4e38f;
    #pragma unroll
    for (int e = 0; e < 4; ++e) {
        int j = j0 + e;
        float v = -3.4e38f;
        if (j < C) {
            float yv = y[e] + ldv(bias, j, f32m);
            stv(out, off_y + (size_t)n * C + j, yv, f32m);
            v = yv + 0.5f * ratio * (t1[e] - 2.f * t2[e] + t3);
            if (j == lab) sLabVal = v;
        }
        vals[e] = v;
        m = fmaxf(m, v);
    }
    m = wave_max(m);
    int lane = tid & 63, wid = tid >> 6;
    if (lane == 0) sb[wid] = m;
    __syncthreads();
    if (tid == 0) sM = fmaxf(fmaxf(sb[0], sb[1]), fmaxf(sb[2], sb[3]));
    __syncthreads();
    m = sM;
    float s = 0.f;
    #pragma unroll
    for (int e = 0; e < 4; ++e) s += expf(vals[e] - m);   // -inf -> 0
    __syncthreads();
    s = wave_sum(s);
    if (lane == 0) sb[wid] = s;
    __syncthreads();
    if (tid == 0) {
        float rl = m + logf(sb[0] + sb[1] + sb[2] + sb[3]) - sLabVal;
        atomicAdd(&misc[0], rl);
        __threadfence();
        int old = atomicAdd((int*)&misc[1], 1);
        if (old == Nn - 1) {
            __threadfence();
            float tot = atomicAdd(&misc[0], 0.f);   // coherent read
            stv(out, 0, tot / (float)Nn, f32m);
        }
    }
}

extern "C" void kernel_launch(void* const* d_in, const int* in_sizes, int n_in,
                              void* d_out, int out_size, void* d_ws, size_t ws_size,
                              hipStream_t stream) {
    const void* feat   = d_in[0];
    const int*  labels = (const int*)d_in[1];
    const void* W      = d_in[2];
    const void* bias   = d_in[3];
    const void* ave    = d_in[4];
    const void* cov    = d_in[5];
    const void* amount = d_in[6];
    const void* ratiop = d_in[7];

    int NA = in_sizes[0];                  // N*A
    int Nn = in_sizes[1];                  // 512
    int C  = in_sizes[3];                  // 1000
    int A  = NA / Nn;                      // 2048
    int CA = in_sizes[2];                  // C*A
    int Cpad = ((C + 255) / 256) * 256;    // 1024
    int nch = A / 1024;                    // 2
    size_t NC = (size_t)Nn * Cpad;

    size_t off_y   = 1;
    size_t off_ave = off_y + (size_t)Nn * C;
    size_t off_cov = off_ave + (size_t)CA;
    size_t off_amt = off_cov + (size_t)CA;

    char* ws = (char*)d_ws;
    int*   w_cnt  = (int*)ws;                          // 1024
    int*   w_off  = w_cnt + 1024;                      // 1024
    int*   w_rows = w_off + 1024;                      // 1024
    float* w_misc = (float*)(w_rows + 1024);           // 16
    float* w_T3p  = w_misc + 16;                       // C*nch (<= 8192)
    float* w_partY  = w_T3p + 8192;                    // KSPLIT*NC
    float* w_partT1 = w_partY + KSPLIT * NC;           // KSPLIT*NC
    float* w_partT2 = w_partT1 + KSPLIT * NC;          // KSPLIT*NC
    u16* w_featb = (u16*)(w_partT2 + KSPLIT * NC);     // NA
    u16* w_Wb    = w_featb + NA;                       // CA
    u16* w_W2b   = w_Wb + CA;                          // CA
    u16* w_Cb    = w_W2b + CA;                         // CA
    u16* w_Gb    = w_Cb + CA;                          // CA

    prep_sort<<<NA / 2048, 256, 0, stream>>>(feat, w_featb, NA, labels,
                                             w_cnt, w_off, w_rows, w_misc, Nn, C);
    dim3 g2(nch, C);
    finalize_stats<<<g2, 256, 0, stream>>>(w_featb, w_cnt, w_off, w_rows,
                                           ave, cov, amount, W, feat,
                                           d_out, off_ave, off_cov, off_amt,
                                           w_Wb, w_W2b, w_Cb, w_Gb, w_T3p, A, nch);
    dim3 g3(Cpad / 128, Nn / 64, KSPLIT);
    triple_gemm_mfma<<<g3, 256, 0, stream>>>(w_featb, w_Wb, w_W2b, w_Cb, w_Gb,
                                             labels, w_partY, w_partT1, w_partT2,
                                             Cpad, A, NC);
    epilogue_rowloss<<<Nn, 256, 0, stream>>>(w_partY, w_partT1, w_partT2, w_T3p,
                                             bias, feat, labels, d_out, off_y,
                                             w_misc, C, Cpad, nch, ratiop, NC, Nn);
}

// Round 10
// 142.671 us; speedup vs baseline: 1.0682x; 1.0682x over previous
//
#include <hip/hip_runtime.h>
#include <hip/hip_bf16.h>

typedef short v8s __attribute__((ext_vector_type(8)));
typedef float v4f __attribute__((ext_vector_type(4)));

#define KSPLIT 4

// ---- dual-dtype element access (f32m: 0 = bf16, 1 = f32) ----
static __device__ __forceinline__ float ldv(const void* p, size_t i, int f32m) {
    if (f32m) return ((const float*)p)[i];
    return __bfloat162float(((const __hip_bfloat16*)p)[i]);
}
static __device__ __forceinline__ void stv(void* p, size_t i, float v, int f32m) {
    if (f32m) ((float*)p)[i] = v;
    else ((__hip_bfloat16*)p)[i] = __float2bfloat16(v);
}
static __device__ __forceinline__ unsigned short f2bu(float x) {
    __hip_bfloat16 h = __float2bfloat16(x);
    return *(unsigned short*)&h;
}
static __device__ __forceinline__ float bu2f(unsigned short u) {
    return __uint_as_float(((unsigned)u) << 16);
}

// Robust scalar decode: handles int32, float32, or bf16-in-low-16 encodings.
static __device__ __forceinline__ float decode_scalar(const void* p) {
    unsigned u = *(const unsigned*)p;
    unsigned e32 = (u >> 23) & 0xff;
    if (e32 >= 97 && e32 <= 160) return __uint_as_float(u);
    unsigned lo = u & 0xffffu;
    unsigned e16 = (lo >> 7) & 0xff;
    if ((u >> 16) == 0 && e16 >= 97 && e16 <= 160)
        return __uint_as_float(lo << 16);
    return (float)(int)u;
}

// Per-block dtype sniff (deterministic; contains a barrier — call unconditionally).
static __device__ __forceinline__ int block_sniff(const void* feat) {
    const __hip_bfloat16* p = (const __hip_bfloat16*)feat;
    float v = __bfloat162float(p[threadIdx.x & 255]);
    int bad = !(fabsf(v) < 1e10f);
    return __syncthreads_or(bad) ? 1 : 0;
}

__device__ __forceinline__ float wave_sum(float v) {
    #pragma unroll
    for (int o = 32; o > 0; o >>= 1) v += __shfl_down(v, o, 64);
    return v;
}
__device__ __forceinline__ float wave_max(float v) {
    #pragma unroll
    for (int o = 32; o > 0; o >>= 1) v = fmaxf(v, __shfl_down(v, o, 64));
    return v;
}

// async global->LDS, 16B per lane, LDS dst = wave-uniform base + lane*16
static __device__ __forceinline__ void ld16(unsigned short* lds, const unsigned short* g) {
    __builtin_amdgcn_global_load_lds(
        (const __attribute__((address_space(1))) unsigned int*)g,
        (__attribute__((address_space(3))) unsigned int*)lds,
        16, 0, 0);
}

// K1: single-block counting sort of labels -> counts[c], offs[c] (exclusive),
// rows[] (row indices grouped by class). LDS only; no global zero-init needed.
__global__ __launch_bounds__(1024) void count_sort(
        const int* __restrict__ labels, int* __restrict__ counts,
        int* __restrict__ offs, int* __restrict__ rows, int Nn, int C) {
    __shared__ int h[1024];
    __shared__ int o[1024];
    __shared__ int cur[1024];
    int tid = threadIdx.x;
    h[tid] = 0;
    __syncthreads();
    for (int i = tid; i < Nn; i += 1024) atomicAdd(&h[labels[i]], 1);
    __syncthreads();
    o[tid] = h[tid];
    __syncthreads();
    for (int d = 1; d < 1024; d <<= 1) {
        int v = (tid >= d) ? o[tid - d] : 0;
        __syncthreads();
        o[tid] += v;
        __syncthreads();
    }
    int excl = o[tid] - h[tid];
    counts[tid] = h[tid];
    offs[tid] = excl;
    cur[tid] = excl;
    __syncthreads();
    for (int i = tid; i < Nn; i += 1024) {
        int pos = atomicAdd(&cur[labels[i]], 1);
        rows[pos] = i;
    }
}

// K2: feat -> bf16 copy, 8 elems/thread (requires total % 2048 == 0).
__global__ __launch_bounds__(256) void prep(
        const void* __restrict__ feat, unsigned short* __restrict__ featb, int total) {
    int f32m = block_sniff(feat);
    int i = (blockIdx.x * 256 + threadIdx.x) * 8;
    if (i >= total) return;
    if (f32m) {
        const float* f = (const float*)feat + i;
        unsigned short r[8];
        #pragma unroll
        for (int u = 0; u < 8; ++u) r[u] = f2bu(f[u]);
        *(v8s*)(featb + i) = *(v8s*)r;
    } else {
        *(v8s*)(featb + i) = *(const v8s*)((const unsigned short*)feat + i);
    }
}

// K3: finalize stats. Block = (class c = blockIdx.y, 256-col chunk = blockIdx.x).
// Computes mean/var by gathering this class's rows from featb (CSR), then
// new_ave/new_cov/new_amount outputs + bf16 GEMM operands + T3 partials.
__global__ __launch_bounds__(256) void finalize_stats(
        const unsigned short* __restrict__ featb,
        const int* __restrict__ counts, const int* __restrict__ offs,
        const int* __restrict__ rows,
        const void* __restrict__ ave, const void* __restrict__ cov,
        const void* __restrict__ amount, const void* __restrict__ W,
        const void* __restrict__ feat,
        void* __restrict__ out, size_t off_ave, size_t off_cov, size_t off_amt,
        unsigned short* __restrict__ Wb, unsigned short* __restrict__ W2b,
        unsigned short* __restrict__ Cb, unsigned short* __restrict__ Gb,
        float* __restrict__ T3p, int A, int A8) {
    __shared__ float sb[4];
    int f32m = block_sniff(feat);
    int c = blockIdx.y;
    int a = blockIdx.x * 256 + threadIdx.x;
    size_t idx = (size_t)c * A + a;
    int cnti = counts[c];
    int start = offs[c];
    float s1 = 0.f, s2 = 0.f;
    for (int i = 0; i < cnti; ++i) {
        float x = bu2f(featb[(size_t)rows[start + i] * A + a]);
        s1 += x;
        s2 += x * x;
    }
    float cnt = (float)cnti;
    float denom = cnti > 0 ? cnt : 1.f;
    float mean = s1 / denom;
    float var = fmaxf((s2 - cnt * mean * mean) / denom, 0.f);
    float amt = ldv(amount, c, f32m);
    float tot = cnt + amt;
    float w = tot > 0.f ? (cnt / tot) : 0.f;   // nan_to_num(0/0) -> 0
    float av = ldv(ave, idx, f32m);
    float cv = ldv(cov, idx, f32m);
    float d = av - mean;
    float ncv = cv * (1.f - w) + var * w + w * (1.f - w) * d * d;
    float nav = av * (1.f - w) + mean * w;
    stv(out, off_cov + idx, ncv, f32m);
    stv(out, off_ave + idx, nav, f32m);
    float wv = ldv(W, idx, f32m);
    Wb[idx] = f2bu(wv);
    W2b[idx] = f2bu(wv * wv);
    Cb[idx] = f2bu(ncv);
    Gb[idx] = f2bu(ncv * wv);
    if (a == 0) stv(out, off_amt + c, amt + cnt, f32m);
    // T3 partial for this (c, chunk): sum of W^2 * ncov
    float s = wave_sum(wv * wv * ncv);
    int lane = threadIdx.x & 63, wid = threadIdx.x >> 6;
    if (lane == 0) sb[wid] = s;
    __syncthreads();
    if (threadIdx.x == 0) T3p[(size_t)c * A8 + blockIdx.x] = sb[0] + sb[1] + sb[2] + sb[3];
}

// K4: split-K fused MFMA triple GEMM -> per-slice partials (no atomics).
// Tile 64n x 64j, BK=32, KSPLIT=4 -> grid (Cpad/64, Nn/64, 4) = 512 blocks.
__global__ __launch_bounds__(256) void triple_gemm_mfma(
        const unsigned short* __restrict__ featb,
        const unsigned short* __restrict__ Wb,
        const unsigned short* __restrict__ W2b,
        const unsigned short* __restrict__ Cb,
        const unsigned short* __restrict__ Gb,
        const int* __restrict__ labels,
        float* __restrict__ partY, float* __restrict__ partT1, float* __restrict__ partT2,
        int Cpad, int A, size_t NC) {
    __shared__ unsigned short sA[10240];   // F:0 C:2048 G:4096 W:6144 W2:8192
    __shared__ int sLab[64];
    int tid = threadIdx.x, wv = tid >> 6, lane = tid & 63;
    int n0 = blockIdx.y * 64, j0 = blockIdx.x * 64;
    int kslice = A / KSPLIT;
    int k0 = blockIdx.z * kslice;
    if (tid < 64) sLab[tid] = labels[n0 + tid];
    __syncthreads();

    int r = lane & 15, q = lane >> 4;
    int fr = wv * 16 + r;
    const unsigned short* pF = featb + (size_t)(n0 + fr) * A + k0 + q * 8;
    int lab = sLab[fr];
    const unsigned short* pC = Cb + (size_t)lab * A + k0 + q * 8;
    const unsigned short* pG = Gb + (size_t)lab * A + k0 + q * 8;
    const unsigned short* pW = Wb + (size_t)(j0 + fr) * A + k0 + q * 8;
    const unsigned short* pQ = W2b + (size_t)(j0 + fr) * A + k0 + q * 8;
    unsigned short* dF = &sA[0    + wv * 512];
    unsigned short* dC = &sA[2048 + wv * 512];
    unsigned short* dG = &sA[4096 + wv * 512];
    unsigned short* dW = &sA[6144 + wv * 512];
    unsigned short* dQ = &sA[8192 + wv * 512];

    v4f aY[4] = {{0,0,0,0},{0,0,0,0},{0,0,0,0},{0,0,0,0}};
    v4f aT1[4] = {{0,0,0,0},{0,0,0,0},{0,0,0,0},{0,0,0,0}};
    v4f aT2[4] = {{0,0,0,0},{0,0,0,0},{0,0,0,0},{0,0,0,0}};

    for (int kk = 0; kk < kslice; kk += 32) {
        ld16(dF, pF); ld16(dC, pC); ld16(dG, pG); ld16(dW, pW); ld16(dQ, pQ);
        pF += 32; pC += 32; pG += 32; pW += 32; pQ += 32;
        __syncthreads();   // drains LDS-DMA (vmcnt) + joins waves
        v8s f = *(v8s*)&sA[0    + wv * 512 + lane * 8];
        v8s c = *(v8s*)&sA[2048 + wv * 512 + lane * 8];
        v8s g = *(v8s*)&sA[4096 + wv * 512 + lane * 8];
        #pragma unroll
        for (int t = 0; t < 4; ++t) {
            v8s w  = *(v8s*)&sA[6144 + t * 512 + lane * 8];
            v8s w2 = *(v8s*)&sA[8192 + t * 512 + lane * 8];
            aY[t]  = __builtin_amdgcn_mfma_f32_16x16x32_bf16(f, w,  aY[t],  0, 0, 0);
            aT1[t] = __builtin_amdgcn_mfma_f32_16x16x32_bf16(c, w2, aT1[t], 0, 0, 0);
            aT2[t] = __builtin_amdgcn_mfma_f32_16x16x32_bf16(g, w,  aT2[t], 0, 0, 0);
        }
        __syncthreads();
    }

    // C/D layout: col = lane&15, row = (lane>>4)*4 + reg.
    float* pY = partY + (size_t)blockIdx.z * NC;
    float* p1 = partT1 + (size_t)blockIdx.z * NC;
    float* p2 = partT2 + (size_t)blockIdx.z * NC;
    int quad = lane >> 4, colb = lane & 15;
    #pragma unroll
    for (int t = 0; t < 4; ++t) {
        int j = j0 + t * 16 + colb;
        #pragma unroll
        for (int rr = 0; rr < 4; ++rr) {
            int n = n0 + wv * 16 + quad * 4 + rr;
            size_t idx = (size_t)n * Cpad + j;
            pY[idx] = aY[t][rr];
            p1[idx] = aT1[t][rr];
            p2[idx] = aT2[t][rr];
        }
    }
}

// K5: fused epilogue + row loss. One block per row n: sum split-K partials,
// add bias, store y, form isda in registers, logsumexp, rowloss[n].
__global__ __launch_bounds__(256) void epilogue_rowloss(
        const float* __restrict__ partY, const float* __restrict__ partT1,
        const float* __restrict__ partT2, const float* __restrict__ T3p,
        const void* __restrict__ bias, const void* __restrict__ feat,
        const int* __restrict__ labels,
        void* __restrict__ out, size_t off_y,
        float* __restrict__ rowloss,
        int C, int Cpad, int A8, const void* ratio_p, size_t NC) {
    __shared__ float sb[4];
    __shared__ float sM;
    __shared__ float sLabVal;
    int f32m = block_sniff(feat);
    int tid = threadIdx.x;
    int n = blockIdx.x;
    int lab = labels[n];
    float t3 = 0.f;
    for (int i = 0; i < A8; ++i) t3 += T3p[(size_t)lab * A8 + i];
    float ratio = decode_scalar(ratio_p);

    float vals[8];
    int nu = Cpad >> 8;
    float m = -3.4e38f;
    for (int u = 0; u < nu; ++u) {
        int j = u * 256 + tid;
        float v = -3.4e38f;
        if (j < C) {
            size_t idx = (size_t)n * Cpad + j;
            float y = 0.f, t1 = 0.f, t2 = 0.f;
            #pragma unroll
            for (int z = 0; z < KSPLIT; ++z) {
                y  += partY[z * NC + idx];
                t1 += partT1[z * NC + idx];
                t2 += partT2[z * NC + idx];
            }
            y += ldv(bias, j, f32m);
            stv(out, off_y + (size_t)n * C + j, y, f32m);
            v = y + 0.5f * ratio * (t1 - 2.f * t2 + t3);
            if (j == lab) sLabVal = v;
        }
        vals[u] = v;
        m = fmaxf(m, v);
    }
    m = wave_max(m);
    int lane = tid & 63, wid = tid >> 6;
    if (lane == 0) sb[wid] = m;
    __syncthreads();
    if (tid == 0) sM = fmaxf(fmaxf(sb[0], sb[1]), fmaxf(sb[2], sb[3]));
    __syncthreads();
    m = sM;
    float s = 0.f;
    for (int u = 0; u < nu; ++u) s += expf(vals[u] - m);   // -inf -> 0
    __syncthreads();
    s = wave_sum(s);
    if (lane == 0) sb[wid] = s;
    __syncthreads();
    if (tid == 0)
        rowloss[n] = m + logf(sb[0] + sb[1] + sb[2] + sb[3]) - sLabVal;
}

// K6: mean of rowloss -> loss scalar (element 0 of out)
__global__ __launch_bounds__(256) void final_loss(
        const float* __restrict__ rowloss, void* __restrict__ out,
        const void* __restrict__ feat, int Nn) {
    __shared__ float sb[4];
    int f32m = block_sniff(feat);
    float s = 0.f;
    for (int i = threadIdx.x; i < Nn; i += 256) s += rowloss[i];
    s = wave_sum(s);
    int lane = threadIdx.x & 63, wid = threadIdx.x >> 6;
    if (lane == 0) sb[wid] = s;
    __syncthreads();
    if (threadIdx.x == 0)
        stv(out, 0, (sb[0] + sb[1] + sb[2] + sb[3]) / (float)Nn, f32m);
}

extern "C" void kernel_launch(void* const* d_in, const int* in_sizes, int n_in,
                              void* d_out, int out_size, void* d_ws, size_t ws_size,
                              hipStream_t stream) {
    const void* feat   = d_in[0];
    const int*  labels = (const int*)d_in[1];
    const void* W      = d_in[2];
    const void* bias   = d_in[3];
    const void* ave    = d_in[4];
    const void* cov    = d_in[5];
    const void* amount = d_in[6];
    const void* ratiop = d_in[7];

    int NA = in_sizes[0];                  // N*A
    int Nn = in_sizes[1];                  // 512
    int C  = in_sizes[3];                  // 1000
    int A  = NA / Nn;                      // 2048
    int CA = in_sizes[2];                  // C*A
    int Cpad = ((C + 255) / 256) * 256;    // 1024
    int A8 = A / 256;                      // 8
    size_t NC = (size_t)Nn * Cpad;

    size_t off_y   = 1;
    size_t off_ave = off_y + (size_t)Nn * C;
    size_t off_cov = off_ave + (size_t)CA;
    size_t off_amt = off_cov + (size_t)CA;

    char* ws = (char*)d_ws;
    int*   w_cnt  = (int*)ws;                          // 1024
    int*   w_off  = w_cnt + 1024;                      // 1024
    int*   w_rows = w_off + 1024;                      // 1024
    float* w_T3p  = (float*)(w_rows + 1024);           // C*A8 (<= 8192)
    float* w_rowls = w_T3p + 8192;                     // 1024
    float* w_partY  = w_rowls + 1024;                  // KSPLIT*NC
    float* w_partT1 = w_partY + KSPLIT * NC;           // KSPLIT*NC
    float* w_partT2 = w_partT1 + KSPLIT * NC;          // KSPLIT*NC
    unsigned short* w_featb = (unsigned short*)(w_partT2 + KSPLIT * NC);  // NA
    unsigned short* w_Wb    = w_featb + NA;            // CA
    unsigned short* w_W2b   = w_Wb + CA;               // CA
    unsigned short* w_Cb    = w_W2b + CA;              // CA
    unsigned short* w_Gb    = w_Cb + CA;               // CA

    count_sort<<<1, 1024, 0, stream>>>(labels, w_cnt, w_off, w_rows, Nn, C);
    prep<<<NA / 2048, 256, 0, stream>>>(feat, w_featb, NA);
    dim3 g2(A8, C);
    finalize_stats<<<g2, 256, 0, stream>>>(w_featb, w_cnt, w_off, w_rows,
                                           ave, cov, amount, W, feat,
                                           d_out, off_ave, off_cov, off_amt,
                                           w_Wb, w_W2b, w_Cb, w_Gb, w_T3p, A, A8);
    dim3 g3(Cpad / 64, Nn / 64, KSPLIT);
    triple_gemm_mfma<<<g3, 256, 0, stream>>>(w_featb, w_Wb, w_W2b, w_Cb, w_Gb,
                                             labels, w_partY, w_partT1, w_partT2,
                                             Cpad, A, NC);
    epilogue_rowloss<<<Nn, 256, 0, stream>>>(w_partY, w_partT1, w_partT2, w_T3p,
                                             bias, feat, labels, d_out, off_y,
                                             w_rowls, C, Cpad, A8, ratiop, NC);
    final_loss<<<1, 256, 0, stream>>>(w_rowls, d_out, feat, Nn);
}